// Round 5
// baseline (578.505 us; speedup 1.0000x reference)
//
#include <hip/hip_runtime.h>
#include <hip/hip_bf16.h>
#include <math.h>

#define HID 768
#define NH 12
#define HD 64
#define BB 2
#define SS 4096
#define MM (BB*SS)   // 8192 rows total

typedef unsigned short u16;
typedef __attribute__((ext_vector_type(8))) short short8;     // 8 bf16 = 4 VGPR (MFMA A/B frag)
typedef __attribute__((ext_vector_type(8))) unsigned short u16x8;
typedef __attribute__((ext_vector_type(4))) float f32x4;      // 16x16 C/D frag
typedef __attribute__((ext_vector_type(16))) float f32x16;    // 32x32 C/D frag

__device__ __forceinline__ u16 f2bf(float f) {
  union { float f; unsigned u; } v; v.f = f;
  return (u16)((v.u + 0x7fffu + ((v.u >> 16) & 1u)) >> 16);   // RNE
}

__device__ __forceinline__ unsigned cvtpk(float lo, float hi) {
  unsigned r;
  asm("v_cvt_pk_bf16_f32 %0, %1, %2" : "=v"(r) : "v"(lo), "v"(hi));
  return r;
}

__device__ __forceinline__ short8 mk8(unsigned a, unsigned b, unsigned c, unsigned d) {
  union { unsigned u[4]; short8 s; } x;
  x.u[0] = a; x.u[1] = b; x.u[2] = c; x.u[3] = d;
  return x.s;
}

// v_permlane32_swap: a' = {a.lo | partner-lo's b}, b' = {partner-hi's a | b.hi}
__device__ __forceinline__ void pls(unsigned &a, unsigned &b) {
  typedef __attribute__((ext_vector_type(2))) unsigned uv2;
  uv2 r = __builtin_amdgcn_permlane32_swap(a, b, false, false);
  a = r[0]; b = r[1];
}

__device__ __forceinline__ float swap_max(float x) {   // max with lane^32, VALU-only
  union { float f; unsigned u; } a, b; a.f = x; b.f = x;
  pls(a.u, b.u);
  return fmaxf(a.f, b.f);
}
__device__ __forceinline__ float swap_add(float x) {   // sum with lane^32, VALU-only
  union { float f; unsigned u; } a, b; a.f = x; b.f = x;
  pls(a.u, b.u);
  return a.f + b.f;
}

#define C2F 0.18033688f        // 0.125 * log2(e)
#define THR2 11.5415603f       // 8 * log2(e)

// ---------------- mask any-nonzero scan (fp32 zeros have zero bits) ----------------
__global__ void mask_scan(const uint4* __restrict__ m, long long n4, int* __restrict__ flag) {
  long long i = (long long)blockIdx.x * blockDim.x + threadIdx.x;
  long long stride = (long long)gridDim.x * blockDim.x;
  unsigned acc = 0;
  for (; i < n4; i += stride) {
    uint4 v = m[i];
    acc |= v.x | v.y | v.z | v.w;
  }
  if (__any(acc != 0)) {
    if ((threadIdx.x & 63) == 0) atomicOr(flag, 1);
  }
}

// ---------------- W [k][n] fp32  ->  Wt [n][k] bf16 ----------------
__global__ void w_transpose(const float* __restrict__ w0, const float* __restrict__ w1,
                            const float* __restrict__ w2, const float* __restrict__ w3,
                            u16* __restrict__ wt) {
  const float* W = (blockIdx.z == 0) ? w0 : (blockIdx.z == 1) ? w1 : (blockIdx.z == 2) ? w2 : w3;
  u16* Wt = wt + (size_t)blockIdx.z * HID * HID;
  __shared__ float tile[64][65];
  int kb = blockIdx.x * 64, nb = blockIdx.y * 64;
  int t = threadIdx.x;
  int r = t >> 2, cg = (t & 3) << 4;
  const float* src = W + (size_t)(kb + r) * HID + nb + cg;
#pragma unroll
  for (int i = 0; i < 4; i++) {
    float4 v = *(const float4*)(src + 4 * i);
    tile[r][cg + 4*i + 0] = v.x;
    tile[r][cg + 4*i + 1] = v.y;
    tile[r][cg + 4*i + 2] = v.z;
    tile[r][cg + 4*i + 3] = v.w;
  }
  __syncthreads();
  u16x8 a, b;
#pragma unroll
  for (int i = 0; i < 8; i++) a[i] = f2bf(tile[cg + i][r]);
#pragma unroll
  for (int i = 0; i < 8; i++) b[i] = f2bf(tile[cg + 8 + i][r]);
  u16* dst = Wt + (size_t)(nb + r) * HID + kb + cg;
  *(u16x8*)dst = a;
  *(u16x8*)(dst + 8) = b;
}

// ---------------- v_bf [bh][s][d] -> vt_bf [bh][d][s] ----------------
__global__ void v_transpose(const u16* __restrict__ v_bf, u16* __restrict__ vt_bf) {
  int bh = blockIdx.y, sb = blockIdx.x * 64;
  __shared__ u16 tile[64][72];
  const u16* src = v_bf + (size_t)bh * SS * HD;
  u16* dst = vt_bf + (size_t)bh * HD * SS;
  int t = threadIdx.x;
  int r = t >> 2, cg = (t & 3) << 4;
  *(u16x8*)(&tile[r][cg])     = *(const u16x8*)(src + (size_t)(sb + r) * HD + cg);
  *(u16x8*)(&tile[r][cg + 8]) = *(const u16x8*)(src + (size_t)(sb + r) * HD + cg + 8);
  __syncthreads();
  u16x8 a, b;
#pragma unroll
  for (int i = 0; i < 8; i++) a[i] = tile[cg + i][r];
#pragma unroll
  for (int i = 0; i < 8; i++) b[i] = tile[cg + 8 + i][r];
  *(u16x8*)(dst + (size_t)r * SS + sb + cg) = a;
  *(u16x8*)(dst + (size_t)r * SS + sb + cg + 8) = b;
}

// ---------------- QKV projection: Y = X @ W + b, bf16 out in [B,H,S,D] ----------------
__launch_bounds__(256)
__global__ void proj_qkv(const float* __restrict__ Xq, const float* __restrict__ Xk,
                         const float* __restrict__ Xv, const u16* __restrict__ wt,
                         const float* __restrict__ bq, const float* __restrict__ bk,
                         const float* __restrict__ bv,
                         u16* __restrict__ qo, u16* __restrict__ ko, u16* __restrict__ vo) {
  int which = blockIdx.z;
  const float* X   = which == 0 ? Xq : which == 1 ? Xk : Xv;
  const u16* Wt    = wt + (size_t)which * HID * HID;
  const float* bias = which == 0 ? bq : which == 1 ? bk : bv;
  u16* out         = which == 0 ? qo : which == 1 ? ko : vo;

  __shared__ u16 Al[128 * 40];
  __shared__ u16 Bl[128 * 40];
  int t = threadIdx.x;
  int mbase = blockIdx.x * 128, nbase = blockIdx.y * 128;
  int wid = t >> 6, lane = t & 63, g = lane >> 4, c = lane & 15;
  int wm = wid >> 1, wn = wid & 1;

  f32x4 acc[4][4];
#pragma unroll
  for (int i = 0; i < 4; i++)
#pragma unroll
    for (int j = 0; j < 4; j++) acc[i][j] = 0.0f;

  int ar = t >> 1, ac = (t & 1) << 4;
  const float* xrow = X  + (size_t)(mbase + ar) * HID + ac;
  const u16*   wrow = Wt + (size_t)(nbase + ar) * HID + ac;
  u16* adst = &Al[ar * 40 + ac];
  u16* bdst = &Bl[ar * 40 + ac];

  for (int k0 = 0; k0 < HID; k0 += 32) {
    float4 x0 = *(const float4*)(xrow + k0);
    float4 x1 = *(const float4*)(xrow + k0 + 4);
    float4 x2 = *(const float4*)(xrow + k0 + 8);
    float4 x3 = *(const float4*)(xrow + k0 + 12);
    u16x8 pa_, pb_;
    pa_[0]=f2bf(x0.x); pa_[1]=f2bf(x0.y); pa_[2]=f2bf(x0.z); pa_[3]=f2bf(x0.w);
    pa_[4]=f2bf(x1.x); pa_[5]=f2bf(x1.y); pa_[6]=f2bf(x1.z); pa_[7]=f2bf(x1.w);
    pb_[0]=f2bf(x2.x); pb_[1]=f2bf(x2.y); pb_[2]=f2bf(x2.z); pb_[3]=f2bf(x2.w);
    pb_[4]=f2bf(x3.x); pb_[5]=f2bf(x3.y); pb_[6]=f2bf(x3.z); pb_[7]=f2bf(x3.w);
    u16x8 w0 = *(const u16x8*)(wrow + k0);
    u16x8 w1 = *(const u16x8*)(wrow + k0 + 8);
    *(u16x8*)adst       = pa_;
    *(u16x8*)(adst + 8) = pb_;
    *(u16x8*)bdst       = w0;
    *(u16x8*)(bdst + 8) = w1;
    __syncthreads();
    short8 af[4], bfr[4];
#pragma unroll
    for (int i = 0; i < 4; i++)
      af[i] = *(const short8*)(&Al[(wm*64 + i*16 + c) * 40 + 8*g]);
#pragma unroll
    for (int i = 0; i < 4; i++)
      bfr[i] = *(const short8*)(&Bl[(wn*64 + i*16 + c) * 40 + 8*g]);
#pragma unroll
    for (int mi = 0; mi < 4; mi++)
#pragma unroll
      for (int ni = 0; ni < 4; ni++)
        acc[mi][ni] = __builtin_amdgcn_mfma_f32_16x16x32_bf16(af[mi], bfr[ni], acc[mi][ni], 0, 0, 0);
    __syncthreads();
  }
#pragma unroll
  for (int ni = 0; ni < 4; ni++) {
    int n = nbase + wn*64 + ni*16 + c;
    float bv_ = bias[n];
    int hh = n >> 6, dd = n & 63;
#pragma unroll
    for (int mi = 0; mi < 4; mi++)
#pragma unroll
      for (int j = 0; j < 4; j++) {
        int m = mbase + wm*64 + mi*16 + 4*g + j;
        int bidx = m >> 12, s_ = m & (SS - 1);
        out[(((size_t)bidx * NH + hh) * SS + s_) * HD + dd] = f2bf(acc[mi][ni][j] + bv_);
      }
  }
}

// ---------------- final projection: out = ctx @ Wo + bo (fp32 out) ----------------
__launch_bounds__(256)
__global__ void proj_out(const u16* __restrict__ X, const u16* __restrict__ Wt,
                         const float* __restrict__ bias, float* __restrict__ out) {
  __shared__ u16 Al[128 * 40];
  __shared__ u16 Bl[128 * 40];
  int t = threadIdx.x;
  int mbase = blockIdx.x * 128, nbase = blockIdx.y * 128;
  int wid = t >> 6, lane = t & 63, g = lane >> 4, c = lane & 15;
  int wm = wid >> 1, wn = wid & 1;

  f32x4 acc[4][4];
#pragma unroll
  for (int i = 0; i < 4; i++)
#pragma unroll
    for (int j = 0; j < 4; j++) acc[i][j] = 0.0f;

  int ar = t >> 1, ac = (t & 1) << 4;
  const u16* xrow = X  + (size_t)(mbase + ar) * HID + ac;
  const u16* wrow = Wt + (size_t)(nbase + ar) * HID + ac;
  u16* adst = &Al[ar * 40 + ac];
  u16* bdst = &Bl[ar * 40 + ac];

  for (int k0 = 0; k0 < HID; k0 += 32) {
    u16x8 a0 = *(const u16x8*)(xrow + k0);
    u16x8 a1 = *(const u16x8*)(xrow + k0 + 8);
    u16x8 w0 = *(const u16x8*)(wrow + k0);
    u16x8 w1 = *(const u16x8*)(wrow + k0 + 8);
    *(u16x8*)adst       = a0;
    *(u16x8*)(adst + 8) = a1;
    *(u16x8*)bdst       = w0;
    *(u16x8*)(bdst + 8) = w1;
    __syncthreads();
    short8 af[4], bfr[4];
#pragma unroll
    for (int i = 0; i < 4; i++)
      af[i] = *(const short8*)(&Al[(wm*64 + i*16 + c) * 40 + 8*g]);
#pragma unroll
    for (int i = 0; i < 4; i++)
      bfr[i] = *(const short8*)(&Bl[(wn*64 + i*16 + c) * 40 + 8*g]);
#pragma unroll
    for (int mi = 0; mi < 4; mi++)
#pragma unroll
      for (int ni = 0; ni < 4; ni++)
        acc[mi][ni] = __builtin_amdgcn_mfma_f32_16x16x32_bf16(af[mi], bfr[ni], acc[mi][ni], 0, 0, 0);
    __syncthreads();
  }
#pragma unroll
  for (int ni = 0; ni < 4; ni++) {
    int n = nbase + wn*64 + ni*16 + c;
    float bv_ = bias[n];
#pragma unroll
    for (int mi = 0; mi < 4; mi++)
#pragma unroll
      for (int j = 0; j < 4; j++) {
        int m = mbase + wm*64 + mi*16 + 4*g + j;
        out[(size_t)m * HID + n] = acc[mi][ni][j] + bv_;
      }
  }
}

// ---------------- flash attention: 32x32 MFMA, swapped QK^T, in-register softmax ----
// Per block: 128 q rows (4 waves x 32). KVBLK=64. K/V^T staged in XOR-swizzled
// [64][64] u16 LDS tiles, double-buffered, 1 barrier/tile. Softmax in exp2 domain;
// all cross-half exchanges via v_permlane32_swap (VALU pipe, no LDS traffic).
__launch_bounds__(256)
__global__ void attn(const u16* __restrict__ q_bf, const u16* __restrict__ k_bf,
                     const u16* __restrict__ vt_bf, const float* __restrict__ mask,
                     const int* __restrict__ flag, u16* __restrict__ ctx) {
  const int qb = blockIdx.x, bh = blockIdx.y;
  const int b = bh / NH, hh = bh - b * NH;
  const u16* Q  = q_bf  + (size_t)bh * SS * HD;
  const u16* K  = k_bf  + (size_t)bh * SS * HD;
  const u16* VT = vt_bf + (size_t)bh * HD * SS;
  const int t = threadIdx.x, wid = t >> 6, lane = t & 63;
  const int c5 = lane & 31, h2 = lane >> 5;
  const int qbase = qb * 128 + wid * 32;
  const int use_mask = *flag;

  __shared__ u16 KV[2 * 8192];   // [buf][ K 64x64 | V^T 64x64 ] swizzled

  // Q B-frags (col = q = c5, k-octet d = 16*dc + 8*h2 + e), live whole kernel
  short8 qf0, qf1, qf2, qf3;
  {
    const u16* qrow = Q + (size_t)(qbase + c5) * HD + 8 * h2;
    qf0 = *(const short8*)(qrow);
    qf1 = *(const short8*)(qrow + 16);
    qf2 = *(const short8*)(qrow + 32);
    qf3 = *(const short8*)(qrow + 48);
  }

  f32x16 o0, o1; o0 = 0.0f; o1 = 0.0f;   // D[q][d]: dt=0 (d 0-31), dt=1 (d 32-63)
  float m2_run = -1e30f, l_run = 0.0f;   // m2 in log2 units

  // staging: thread t -> row sr, 32B (granules 2*sq, 2*sq+1), swizzled slots
  const int sr = t >> 2, sq = t & 3;
  const int o_k0 = sr * 64 + (((2 * sq) ^ (sr & 7)) * 8);   // u16 index; pair at ^8
  const u16* kp = K  + (size_t)sr * HD + sq * 16;
  const u16* vp = VT + (size_t)sr * SS + sq * 16;
  u16x8 rk0 = *(const u16x8*)kp, rk1 = *(const u16x8*)(kp + 8);
  u16x8 rv0 = *(const u16x8*)vp, rv1 = *(const u16x8*)(vp + 8);

  const int sw = c5 & 7;
  const int krow0 = c5 * 64, krow1 = (32 + c5) * 64;

  for (int tl = 0; tl < SS / 64; ++tl) {
    const int bufo = (tl & 1) * 8192;
    u16* kd = KV + bufo;
    *(u16x8*)(kd + o_k0)              = rk0;
    *(u16x8*)(kd + (o_k0 ^ 8))        = rk1;
    *(u16x8*)(kd + 4096 + o_k0)       = rv0;
    *(u16x8*)(kd + 4096 + (o_k0 ^ 8)) = rv1;
    if (tl < SS / 64 - 1) {            // issue next tile early; hides under compute
      kp += 64 * HD; vp += 64;
      rk0 = *(const u16x8*)kp; rk1 = *(const u16x8*)(kp + 8);
      rv0 = *(const u16x8*)vp; rv1 = *(const u16x8*)(vp + 8);
    }
    __syncthreads();
    const u16* Kb = KV + bufo;
    const u16* Vb = KV + bufo + 4096;

    // swapped QK^T: D[key][q], col=q=c5, row=key=(reg&3)+8*(reg>>2)+4*h2 (+32*kt)
    f32x16 s0, s1; s0 = 0.0f; s1 = 0.0f;
    __builtin_amdgcn_s_setprio(1);
#pragma unroll
    for (int dc = 0; dc < 4; ++dc) {
      short8 qv = dc == 0 ? qf0 : dc == 1 ? qf1 : dc == 2 ? qf2 : qf3;
      short8 ka = *(const short8*)(Kb + krow0 + (((2 * dc + h2) ^ sw) * 8));
      s0 = __builtin_amdgcn_mfma_f32_32x32x16_bf16(ka, qv, s0, 0, 0, 0);
    }
#pragma unroll
    for (int dc = 0; dc < 4; ++dc) {
      short8 qv = dc == 0 ? qf0 : dc == 1 ? qf1 : dc == 2 ? qf2 : qf3;
      short8 ka = *(const short8*)(Kb + krow1 + (((2 * dc + h2) ^ sw) * 8));
      s1 = __builtin_amdgcn_mfma_f32_32x32x16_bf16(ka, qv, s1, 0, 0, 0);
    }
    __builtin_amdgcn_s_setprio(0);

    if (use_mask) {   // (raw + 8*mask) keeps one post-scale constant C2F
      const float* mrow = mask + ((size_t)b * SS + (qbase + c5)) * SS + (size_t)tl * 64;
#pragma unroll
      for (int j = 0; j < 16; ++j) {
        const int row = (j & 3) + 8 * (j >> 2) + 4 * h2;
        s0[j] = fmaf(mrow[row],      8.0f, s0[j]);
        s1[j] = fmaf(mrow[32 + row], 8.0f, s1[j]);
      }
    }

    // row max (all scores for q=c5 live on lanes c5, c5+32)
    float rm = fmaxf(s0[0], s1[0]);
#pragma unroll
    for (int j = 1; j < 16; ++j) rm = fmaxf(rm, fmaxf(s0[j], s1[j]));
    const float pmax2 = swap_max(rm) * C2F;   // log2 units

    // defer-max (T13): rescale only when tile max grows past m2_run + 8*log2e
    if (!__all(pmax2 <= m2_run + THR2)) {
      const float mn = fmaxf(m2_run, pmax2);
      const float ef = exp2f(m2_run - mn);
      m2_run = mn; l_run *= ef;
#pragma unroll
      for (int j = 0; j < 16; ++j) {
        const int row = (j & 3) + 8 * (j >> 2) + 4 * h2;
        const float eb = __shfl(ef, row);   // O rows need ef of q=row (rare path)
        o0[j] *= eb; o1[j] *= eb;
      }
    }

    // p = exp2(s*C2F - m2_run), tile sum
    float ts = 0.0f;
#pragma unroll
    for (int j = 0; j < 16; ++j) { float p = exp2f(fmaf(s0[j], C2F, -m2_run)); s0[j] = p; ts += p; }
#pragma unroll
    for (int j = 0; j < 16; ++j) { float p = exp2f(fmaf(s1[j], C2F, -m2_run)); s1[j] = p; ts += p; }
    l_run += swap_add(ts);

    // pack P to bf16 dwords: w[jg][p] = keys 8*jg + 2*p + 4*h2 (+32 for y*)
    unsigned w00 = cvtpk(s0[0],  s0[1]),  w01 = cvtpk(s0[2],  s0[3]);
    unsigned w10 = cvtpk(s0[4],  s0[5]),  w11 = cvtpk(s0[6],  s0[7]);
    unsigned w20 = cvtpk(s0[8],  s0[9]),  w21 = cvtpk(s0[10], s0[11]);
    unsigned w30 = cvtpk(s0[12], s0[13]), w31 = cvtpk(s0[14], s0[15]);
    unsigned y00 = cvtpk(s1[0],  s1[1]),  y01 = cvtpk(s1[2],  s1[3]);
    unsigned y10 = cvtpk(s1[4],  s1[5]),  y11 = cvtpk(s1[6],  s1[7]);
    unsigned y20 = cvtpk(s1[8],  s1[9]),  y21 = cvtpk(s1[10], s1[11]);
    unsigned y30 = cvtpk(s1[12], s1[13]), y31 = cvtpk(s1[14], s1[15]);

    // cross-half exchange via permlane32_swap -> A-frags (row=q=c5, k-octet 8*h2+e)
    pls(w00, w10); pls(w01, w11);   // p0: keys 0-15 chunk
    pls(w20, w30); pls(w21, w31);   // p1: keys 16-31
    pls(y00, y10); pls(y01, y11);   // p2: keys 32-47
    pls(y20, y30); pls(y21, y31);   // p3: keys 48-63
    short8 p0 = mk8(w00, w01, w10, w11);
    short8 p1 = mk8(w20, w21, w30, w31);
    short8 p2 = mk8(y00, y01, y10, y11);
    short8 p3 = mk8(y20, y21, y30, y31);

    // PV: D[q][d] += P[q][k16] * V[k16][d]  (B-frag = V^T rows, swizzled reads)
    __builtin_amdgcn_s_setprio(1);
#pragma unroll
    for (int kc = 0; kc < 4; ++kc) {
      short8 pa = kc == 0 ? p0 : kc == 1 ? p1 : kc == 2 ? p2 : p3;
      short8 v0 = *(const short8*)(Vb + krow0 + (((2 * kc + h2) ^ sw) * 8));
      o0 = __builtin_amdgcn_mfma_f32_32x32x16_bf16(pa, v0, o0, 0, 0, 0);
      short8 v1 = *(const short8*)(Vb + krow1 + (((2 * kc + h2) ^ sw) * 8));
      o1 = __builtin_amdgcn_mfma_f32_32x32x16_bf16(pa, v1, o1, 0, 0, 0);
    }
    __builtin_amdgcn_s_setprio(0);
  }

  // epilogue: O row q = (j&3)+8*(j>>2)+4*h2, col d = 32*dt + c5; normalize by l[q]
  const float inv = 1.0f / l_run;
  u16* cbase = ctx + ((size_t)b * SS) * HID + hh * HD;
#pragma unroll
  for (int j = 0; j < 16; ++j) {
    const int row = (j & 3) + 8 * (j >> 2) + 4 * h2;
    const float ib = __shfl(inv, row);
    u16* crow = cbase + (size_t)(qbase + row) * HID;
    crow[c5]      = f2bf(o0[j] * ib);
    crow[32 + c5] = f2bf(o1[j] * ib);
  }
}

// ---------------------------------------------------------------------------------
extern "C" void kernel_launch(void* const* d_in, const int* in_sizes, int n_in,
                              void* d_out, int out_size, void* d_ws, size_t ws_size,
                              hipStream_t stream) {
  (void)in_sizes; (void)n_in; (void)out_size; (void)ws_size;
  const float* key   = (const float*)d_in[0];
  const float* value = (const float*)d_in[1];
  const float* query = (const float*)d_in[2];
  const float* mask  = (const float*)d_in[3];
  const float* Wq = (const float*)d_in[4];
  const float* bq = (const float*)d_in[5];
  const float* Wk = (const float*)d_in[6];
  const float* bk = (const float*)d_in[7];
  const float* Wv = (const float*)d_in[8];
  const float* bv = (const float*)d_in[9];
  const float* Wo = (const float*)d_in[10];
  const float* bo = (const float*)d_in[11];

  char* ws = (char*)d_ws;
  const size_t WSZ = (size_t)HID * HID * 2;         // one bf16 weight: 1.18 MB
  const size_t QSZ = (size_t)BB * NH * SS * HD * 2; // q/k/v/ctx bf16: 12.58 MB
  u16* w_t   = (u16*)ws;                            // 4 weights transposed (q,k,v,o)
  u16* q_bf  = (u16*)(ws + 4*WSZ);
  u16* k_bf  = (u16*)(ws + 4*WSZ + QSZ);
  u16* v_bf  = (u16*)(ws + 4*WSZ + 2*QSZ);
  u16* vt_bf = (u16*)(ws + 4*WSZ + 3*QSZ);
  u16* ctx   = (u16*)(ws + 4*WSZ + 4*QSZ);
  int* flag  = (int*)(ws + 4*WSZ + 5*QSZ);          // total ~64.5 MB

  hipMemsetAsync(flag, 0, 4, stream);
  mask_scan<<<2048, 256, 0, stream>>>((const uint4*)mask, (long long)BB*SS*SS/4, flag);
  w_transpose<<<dim3(12, 12, 4), 256, 0, stream>>>(Wq, Wk, Wv, Wo, w_t);
  proj_qkv<<<dim3(MM/128, HID/128, 3), 256, 0, stream>>>(query, key, value, w_t,
                                                         bq, bk, bv, q_bf, k_bf, v_bf);
  v_transpose<<<dim3(SS/64, BB*NH), 256, 0, stream>>>(v_bf, vt_bf);
  attn<<<dim3(SS/128, BB*NH), 256, 0, stream>>>(q_bf, k_bf, vt_bf, mask, flag, ctx);
  proj_out<<<dim3(MM/128, HID/128), 256, 0, stream>>>(ctx, w_t + 3*(size_t)HID*HID, bo,
                                                      (float*)d_out);
}

// Round 7
// 516.533 us; speedup vs baseline: 1.1200x; 1.1200x over previous
//
#include <hip/hip_runtime.h>
#include <hip/hip_bf16.h>
#include <math.h>

#define HID 768
#define NH 12
#define HD 64
#define BB 2
#define SS 4096
#define MM (BB*SS)   // 8192 rows total

typedef unsigned short u16;
typedef __attribute__((ext_vector_type(8))) short short8;     // 8 bf16 = 4 VGPR (MFMA A/B frag)
typedef __attribute__((ext_vector_type(8))) unsigned short u16x8;
typedef __attribute__((ext_vector_type(4))) float f32x4;      // 16x16 C/D frag
typedef __attribute__((ext_vector_type(16))) float f32x16;    // 32x32 C/D frag

__device__ __forceinline__ u16 f2bf(float f) {
  union { float f; unsigned u; } v; v.f = f;
  return (u16)((v.u + 0x7fffu + ((v.u >> 16) & 1u)) >> 16);   // RNE
}

__device__ __forceinline__ unsigned cvtpk(float lo, float hi) {
  unsigned r;
  asm("v_cvt_pk_bf16_f32 %0, %1, %2" : "=v"(r) : "v"(lo), "v"(hi));
  return r;
}

__device__ __forceinline__ float max3(float a, float b, float c) {
  float r;
  asm("v_max3_f32 %0, %1, %2, %3" : "=v"(r) : "v"(a), "v"(b), "v"(c));
  return r;
}

__device__ __forceinline__ float exp2r(float x) {   // raw v_exp_f32, no libm fixup
  float r;
  asm("v_exp_f32 %0, %1" : "=v"(r) : "v"(x));
  return r;
}

__device__ __forceinline__ float rcpr(float x) {    // raw v_rcp_f32 (1 ulp, fine for bf16 out)
  float r;
  asm("v_rcp_f32 %0, %1" : "=v"(r) : "v"(x));
  return r;
}

__device__ __forceinline__ short8 mk8(unsigned a, unsigned b, unsigned c, unsigned d) {
  union { unsigned u[4]; short8 s; } x;
  x.u[0] = a; x.u[1] = b; x.u[2] = c; x.u[3] = d;
  return x.s;
}

__device__ __forceinline__ u16x8 mku16(unsigned a, unsigned b, unsigned c, unsigned d) {
  union { unsigned u[4]; u16x8 s; } x;
  x.u[0] = a; x.u[1] = b; x.u[2] = c; x.u[3] = d;
  return x.s;
}

// v_permlane32_swap: a' = {a.lo | partner-lo's b}, b' = {partner-hi's a | b.hi}
__device__ __forceinline__ void pls(unsigned &a, unsigned &b) {
  typedef __attribute__((ext_vector_type(2))) unsigned uv2;
  uv2 r = __builtin_amdgcn_permlane32_swap(a, b, false, false);
  a = r[0]; b = r[1];
}

__device__ __forceinline__ float swap_max(float x) {   // max with lane^32, VALU-only
  union { float f; unsigned u; } a, b; a.f = x; b.f = x;
  pls(a.u, b.u);
  return fmaxf(a.f, b.f);
}

#define C2F 0.18033688f        // 0.125 * log2(e)
#define THR2 11.5415603f       // 8 * log2(e)

// ---------------- mask any-nonzero scan (fp32 zeros have zero bits) ----------------
__global__ void mask_scan(const uint4* __restrict__ m, long long n4, int* __restrict__ flag) {
  long long i = (long long)blockIdx.x * blockDim.x + threadIdx.x;
  long long stride = (long long)gridDim.x * blockDim.x;
  unsigned acc = 0;
  for (; i < n4; i += stride) {
    uint4 v = m[i];
    acc |= v.x | v.y | v.z | v.w;
  }
  if (__any(acc != 0)) {
    if ((threadIdx.x & 63) == 0) atomicOr(flag, 1);
  }
}

// ---------------- W [k][n] fp32  ->  Wt [n][k] bf16 ----------------
__global__ void w_transpose(const float* __restrict__ w0, const float* __restrict__ w1,
                            const float* __restrict__ w2, const float* __restrict__ w3,
                            u16* __restrict__ wt) {
  const float* W = (blockIdx.z == 0) ? w0 : (blockIdx.z == 1) ? w1 : (blockIdx.z == 2) ? w2 : w3;
  u16* Wt = wt + (size_t)blockIdx.z * HID * HID;
  __shared__ float tile[64][65];
  int kb = blockIdx.x * 64, nb = blockIdx.y * 64;
  int t = threadIdx.x;
  int r = t >> 2, cg = (t & 3) << 4;
  const float* src = W + (size_t)(kb + r) * HID + nb + cg;
#pragma unroll
  for (int i = 0; i < 4; i++) {
    float4 v = *(const float4*)(src + 4 * i);
    tile[r][cg + 4*i + 0] = v.x;
    tile[r][cg + 4*i + 1] = v.y;
    tile[r][cg + 4*i + 2] = v.z;
    tile[r][cg + 4*i + 3] = v.w;
  }
  __syncthreads();
  u16x8 a, b;
#pragma unroll
  for (int i = 0; i < 8; i++) a[i] = f2bf(tile[cg + i][r]);
#pragma unroll
  for (int i = 0; i < 8; i++) b[i] = f2bf(tile[cg + 8 + i][r]);
  u16* dst = Wt + (size_t)(nb + r) * HID + kb + cg;
  *(u16x8*)dst = a;
  *(u16x8*)(dst + 8) = b;
}

// ---------------- v_bf [bh][s][d] -> vt_bf [bh][d][s] ----------------
__global__ void v_transpose(const u16* __restrict__ v_bf, u16* __restrict__ vt_bf) {
  int bh = blockIdx.y, sb = blockIdx.x * 64;
  __shared__ u16 tile[64][72];
  const u16* src = v_bf + (size_t)bh * SS * HD;
  u16* dst = vt_bf + (size_t)bh * HD * SS;
  int t = threadIdx.x;
  int r = t >> 2, cg = (t & 3) << 4;
  *(u16x8*)(&tile[r][cg])     = *(const u16x8*)(src + (size_t)(sb + r) * HD + cg);
  *(u16x8*)(&tile[r][cg + 8]) = *(const u16x8*)(src + (size_t)(sb + r) * HD + cg + 8);
  __syncthreads();
  u16x8 a, b;
#pragma unroll
  for (int i = 0; i < 8; i++) a[i] = tile[cg + i][r];
#pragma unroll
  for (int i = 0; i < 8; i++) b[i] = tile[cg + 8 + i][r];
  *(u16x8*)(dst + (size_t)r * SS + sb + cg) = a;
  *(u16x8*)(dst + (size_t)r * SS + sb + cg + 8) = b;
}

// ---------------- QKV projection: Y = X @ W + b, bf16 out in [B,H,S,D] ----------------
__launch_bounds__(256)
__global__ void proj_qkv(const float* __restrict__ Xq, const float* __restrict__ Xk,
                         const float* __restrict__ Xv, const u16* __restrict__ wt,
                         const float* __restrict__ bq, const float* __restrict__ bk,
                         const float* __restrict__ bv,
                         u16* __restrict__ qo, u16* __restrict__ ko, u16* __restrict__ vo) {
  int which = blockIdx.z;
  const float* X   = which == 0 ? Xq : which == 1 ? Xk : Xv;
  const u16* Wt    = wt + (size_t)which * HID * HID;
  const float* bias = which == 0 ? bq : which == 1 ? bk : bv;
  u16* out         = which == 0 ? qo : which == 1 ? ko : vo;

  __shared__ u16 Al[128 * 40];
  __shared__ u16 Bl[128 * 40];
  int t = threadIdx.x;
  int mbase = blockIdx.x * 128, nbase = blockIdx.y * 128;
  int wid = t >> 6, lane = t & 63, g = lane >> 4, c = lane & 15;
  int wm = wid >> 1, wn = wid & 1;

  f32x4 acc[4][4];
#pragma unroll
  for (int i = 0; i < 4; i++)
#pragma unroll
    for (int j = 0; j < 4; j++) acc[i][j] = 0.0f;

  int ar = t >> 1, ac = (t & 1) << 4;
  const float* xrow = X  + (size_t)(mbase + ar) * HID + ac;
  const u16*   wrow = Wt + (size_t)(nbase + ar) * HID + ac;
  u16* adst = &Al[ar * 40 + ac];
  u16* bdst = &Bl[ar * 40 + ac];

  for (int k0 = 0; k0 < HID; k0 += 32) {
    float4 x0 = *(const float4*)(xrow + k0);
    float4 x1 = *(const float4*)(xrow + k0 + 4);
    float4 x2 = *(const float4*)(xrow + k0 + 8);
    float4 x3 = *(const float4*)(xrow + k0 + 12);
    // pack fp32 -> bf16 via v_cvt_pk (RNE), 16 ops for 32 floats
    u16x8 pa_ = mku16(cvtpk(x0.x, x0.y), cvtpk(x0.z, x0.w),
                      cvtpk(x1.x, x1.y), cvtpk(x1.z, x1.w));
    u16x8 pb_ = mku16(cvtpk(x2.x, x2.y), cvtpk(x2.z, x2.w),
                      cvtpk(x3.x, x3.y), cvtpk(x3.z, x3.w));
    u16x8 w0 = *(const u16x8*)(wrow + k0);
    u16x8 w1 = *(const u16x8*)(wrow + k0 + 8);
    *(u16x8*)adst       = pa_;
    *(u16x8*)(adst + 8) = pb_;
    *(u16x8*)bdst       = w0;
    *(u16x8*)(bdst + 8) = w1;
    __syncthreads();
    short8 af[4], bfr[4];
#pragma unroll
    for (int i = 0; i < 4; i++)
      af[i] = *(const short8*)(&Al[(wm*64 + i*16 + c) * 40 + 8*g]);
#pragma unroll
    for (int i = 0; i < 4; i++)
      bfr[i] = *(const short8*)(&Bl[(wn*64 + i*16 + c) * 40 + 8*g]);
#pragma unroll
    for (int mi = 0; mi < 4; mi++)
#pragma unroll
      for (int ni = 0; ni < 4; ni++)
        acc[mi][ni] = __builtin_amdgcn_mfma_f32_16x16x32_bf16(af[mi], bfr[ni], acc[mi][ni], 0, 0, 0);
    __syncthreads();
  }
#pragma unroll
  for (int ni = 0; ni < 4; ni++) {
    int n = nbase + wn*64 + ni*16 + c;
    float bv_ = bias[n];
    int hh = n >> 6, dd = n & 63;
#pragma unroll
    for (int mi = 0; mi < 4; mi++)
#pragma unroll
      for (int j = 0; j < 4; j++) {
        int m = mbase + wm*64 + mi*16 + 4*g + j;
        int bidx = m >> 12, s_ = m & (SS - 1);
        out[(((size_t)bidx * NH + hh) * SS + s_) * HD + dd] = f2bf(acc[mi][ni][j] + bv_);
      }
  }
}

// ---------------- final projection: out = ctx @ Wo + bo (fp32 out) ----------------
__launch_bounds__(256)
__global__ void proj_out(const u16* __restrict__ X, const u16* __restrict__ Wt,
                         const float* __restrict__ bias, float* __restrict__ out) {
  __shared__ u16 Al[128 * 40];
  __shared__ u16 Bl[128 * 40];
  int t = threadIdx.x;
  int mbase = blockIdx.x * 128, nbase = blockIdx.y * 128;
  int wid = t >> 6, lane = t & 63, g = lane >> 4, c = lane & 15;
  int wm = wid >> 1, wn = wid & 1;

  f32x4 acc[4][4];
#pragma unroll
  for (int i = 0; i < 4; i++)
#pragma unroll
    for (int j = 0; j < 4; j++) acc[i][j] = 0.0f;

  int ar = t >> 1, ac = (t & 1) << 4;
  const u16* xrow = X  + (size_t)(mbase + ar) * HID + ac;
  const u16* wrow = Wt + (size_t)(nbase + ar) * HID + ac;
  u16* adst = &Al[ar * 40 + ac];
  u16* bdst = &Bl[ar * 40 + ac];

  for (int k0 = 0; k0 < HID; k0 += 32) {
    u16x8 a0 = *(const u16x8*)(xrow + k0);
    u16x8 a1 = *(const u16x8*)(xrow + k0 + 8);
    u16x8 w0 = *(const u16x8*)(wrow + k0);
    u16x8 w1 = *(const u16x8*)(wrow + k0 + 8);
    *(u16x8*)adst       = a0;
    *(u16x8*)(adst + 8) = a1;
    *(u16x8*)bdst       = w0;
    *(u16x8*)(bdst + 8) = w1;
    __syncthreads();
    short8 af[4], bfr[4];
#pragma unroll
    for (int i = 0; i < 4; i++)
      af[i] = *(const short8*)(&Al[(wm*64 + i*16 + c) * 40 + 8*g]);
#pragma unroll
    for (int i = 0; i < 4; i++)
      bfr[i] = *(const short8*)(&Bl[(wn*64 + i*16 + c) * 40 + 8*g]);
#pragma unroll
    for (int mi = 0; mi < 4; mi++)
#pragma unroll
      for (int ni = 0; ni < 4; ni++)
        acc[mi][ni] = __builtin_amdgcn_mfma_f32_16x16x32_bf16(af[mi], bfr[ni], acc[mi][ni], 0, 0, 0);
    __syncthreads();
  }
#pragma unroll
  for (int ni = 0; ni < 4; ni++) {
    int n = nbase + wn*64 + ni*16 + c;
    float bv_ = bias[n];
#pragma unroll
    for (int mi = 0; mi < 4; mi++)
#pragma unroll
      for (int j = 0; j < 4; j++) {
        int m = mbase + wm*64 + mi*16 + 4*g + j;
        out[(size_t)m * HID + n] = acc[mi][ni][j] + bv_;
      }
  }
}

// ---------------- flash attention: 32x32 MFMA, swapped QK^T, in-register softmax ----
// Per block: 128 q rows (4 waves x 32). KVBLK=64. K/V^T staged in XOR-swizzled
// [64][64] u16 LDS tiles, double-buffered, 1 barrier/tile. exp2-domain softmax;
// cross-half exchange via permlane32_swap; row-sum l via ones-MFMA (idle MFMA pipe);
// row-max via v_max3 tree (depth 4 vs 31-op chain). No setprio (m190 regression mode).
__launch_bounds__(256)
__global__ void attn(const u16* __restrict__ q_bf, const u16* __restrict__ k_bf,
                     const u16* __restrict__ vt_bf, const float* __restrict__ mask,
                     const int* __restrict__ flag, u16* __restrict__ ctx) {
  const int qb = blockIdx.x, bh = blockIdx.y;
  const int b = bh / NH, hh = bh - b * NH;
  const u16* Q  = q_bf  + (size_t)bh * SS * HD;
  const u16* K  = k_bf  + (size_t)bh * SS * HD;
  const u16* VT = vt_bf + (size_t)bh * HD * SS;
  const int t = threadIdx.x, wid = t >> 6, lane = t & 63;
  const int c5 = lane & 31, h2 = lane >> 5;
  const int qbase = qb * 128 + wid * 32;
  const int use_mask = *flag;

  __shared__ u16 KV[2 * 8192];   // [buf][ K 64x64 | V^T 64x64 ] swizzled

  // Q B-frags (col = q = c5, k-octet d = 16*dc + 8*h2 + e), live whole kernel
  short8 qf0, qf1, qf2, qf3;
  {
    const u16* qrow = Q + (size_t)(qbase + c5) * HD + 8 * h2;
    qf0 = *(const short8*)(qrow);
    qf1 = *(const short8*)(qrow + 16);
    qf2 = *(const short8*)(qrow + 32);
    qf3 = *(const short8*)(qrow + 48);
  }

  f32x16 o0, o1, lacc; o0 = 0.0f; o1 = 0.0f; lacc = 0.0f;
  float m2_run = -1e30f;                 // running max, log2 units

  const short8 onesf = mk8(0x3F803F80u, 0x3F803F80u, 0x3F803F80u, 0x3F803F80u); // bf16 1.0 x8

  // staging: thread t -> row sr, 32B (granules 2*sq, 2*sq+1), swizzled slots
  const int sr = t >> 2, sq = t & 3;
  const int o_k0 = sr * 64 + (((2 * sq) ^ (sr & 7)) * 8);   // u16 index; pair at ^8
  const u16* kp = K  + (size_t)sr * HD + sq * 16;
  const u16* vp = VT + (size_t)sr * SS + sq * 16;
  u16x8 rk0 = *(const u16x8*)kp, rk1 = *(const u16x8*)(kp + 8);
  u16x8 rv0 = *(const u16x8*)vp, rv1 = *(const u16x8*)(vp + 8);

  const int sw = c5 & 7;
  const int krow0 = c5 * 64, krow1 = (32 + c5) * 64;

  for (int tl = 0; tl < SS / 64; ++tl) {
    const int bufo = (tl & 1) * 8192;
    u16* kd = KV + bufo;
    *(u16x8*)(kd + o_k0)              = rk0;
    *(u16x8*)(kd + (o_k0 ^ 8))        = rk1;
    *(u16x8*)(kd + 4096 + o_k0)       = rv0;
    *(u16x8*)(kd + 4096 + (o_k0 ^ 8)) = rv1;
    if (tl < SS / 64 - 1) {            // issue next tile early; hides under compute
      kp += 64 * HD; vp += 64;
      rk0 = *(const u16x8*)kp; rk1 = *(const u16x8*)(kp + 8);
      rv0 = *(const u16x8*)vp; rv1 = *(const u16x8*)(vp + 8);
    }
    __syncthreads();
    const u16* Kb = KV + bufo;
    const u16* Vb = KV + bufo + 4096;

    // swapped QK^T: D[key][q], col=q=c5, row=key=(reg&3)+8*(reg>>2)+4*h2 (+32*kt)
    f32x16 s0, s1; s0 = 0.0f; s1 = 0.0f;
#pragma unroll
    for (int dc = 0; dc < 4; ++dc) {
      short8 qv = dc == 0 ? qf0 : dc == 1 ? qf1 : dc == 2 ? qf2 : qf3;
      short8 ka = *(const short8*)(Kb + krow0 + (((2 * dc + h2) ^ sw) * 8));
      s0 = __builtin_amdgcn_mfma_f32_32x32x16_bf16(ka, qv, s0, 0, 0, 0);
    }
#pragma unroll
    for (int dc = 0; dc < 4; ++dc) {
      short8 qv = dc == 0 ? qf0 : dc == 1 ? qf1 : dc == 2 ? qf2 : qf3;
      short8 ka = *(const short8*)(Kb + krow1 + (((2 * dc + h2) ^ sw) * 8));
      s1 = __builtin_amdgcn_mfma_f32_32x32x16_bf16(ka, qv, s1, 0, 0, 0);
    }

    if (use_mask) {   // (raw + 8*mask) keeps one post-scale constant C2F
      const float* mrow = mask + ((size_t)b * SS + (qbase + c5)) * SS + (size_t)tl * 64;
#pragma unroll
      for (int j = 0; j < 16; ++j) {
        const int row = (j & 3) + 8 * (j >> 2) + 4 * h2;
        s0[j] = fmaf(mrow[row],      8.0f, s0[j]);
        s1[j] = fmaf(mrow[32 + row], 8.0f, s1[j]);
      }
    }

    // row max via v_max3 tree (depth 4, 16 ops)
    float a0 = max3(s0[0], s0[1], s0[2]),   a1 = max3(s0[3], s0[4], s0[5]);
    float a2 = max3(s0[6], s0[7], s0[8]),   a3 = max3(s0[9], s0[10], s0[11]);
    float a4 = max3(s0[12], s0[13], s0[14]);
    float b0 = max3(s1[0], s1[1], s1[2]),   b1 = max3(s1[3], s1[4], s1[5]);
    float b2 = max3(s1[6], s1[7], s1[8]),   b3 = max3(s1[9], s1[10], s1[11]);
    float b4 = max3(s1[12], s1[13], s1[14]);
    float c0 = max3(a0, a1, a2), c1 = max3(a3, a4, s0[15]);
    float c2 = max3(b0, b1, b2), c3 = max3(b3, b4, s1[15]);
    float rm = fmaxf(max3(c0, c1, c2), c3);
    const float pmax2 = swap_max(rm) * C2F;   // log2 units

    // defer-max (T13): rescale only when tile max grows past m2_run + 8*log2e
    if (!__all(pmax2 <= m2_run + THR2)) {
      const float mn = fmaxf(m2_run, pmax2);
      const float ef = exp2r(m2_run - mn);
      m2_run = mn;
#pragma unroll
      for (int j = 0; j < 16; ++j) {
        const int row = (j & 3) + 8 * (j >> 2) + 4 * h2;
        const float eb = __shfl(ef, row);   // O rows need ef of q=row (rare path)
        o0[j] *= eb; o1[j] *= eb; lacc[j] *= eb;
      }
    }

    // p = exp2(s*C2F - m2_run)  (raw v_exp_f32; arg <= 0 plus defer headroom)
#pragma unroll
    for (int j = 0; j < 16; ++j) s0[j] = exp2r(fmaf(s0[j], C2F, -m2_run));
#pragma unroll
    for (int j = 0; j < 16; ++j) s1[j] = exp2r(fmaf(s1[j], C2F, -m2_run));

    // pack P to bf16 dwords: w[jg][p] = keys 8*jg + 2*p + 4*h2 (+32 for y*)
    unsigned w00 = cvtpk(s0[0],  s0[1]),  w01 = cvtpk(s0[2],  s0[3]);
    unsigned w10 = cvtpk(s0[4],  s0[5]),  w11 = cvtpk(s0[6],  s0[7]);
    unsigned w20 = cvtpk(s0[8],  s0[9]),  w21 = cvtpk(s0[10], s0[11]);
    unsigned w30 = cvtpk(s0[12], s0[13]), w31 = cvtpk(s0[14], s0[15]);
    unsigned y00 = cvtpk(s1[0],  s1[1]),  y01 = cvtpk(s1[2],  s1[3]);
    unsigned y10 = cvtpk(s1[4],  s1[5]),  y11 = cvtpk(s1[6],  s1[7]);
    unsigned y20 = cvtpk(s1[8],  s1[9]),  y21 = cvtpk(s1[10], s1[11]);
    unsigned y30 = cvtpk(s1[12], s1[13]), y31 = cvtpk(s1[14], s1[15]);

    // cross-half exchange via permlane32_swap -> A-frags (row=q=c5, k-octet 8*h2+e)
    pls(w00, w10); pls(w01, w11);   // p0: keys 0-15 chunk
    pls(w20, w30); pls(w21, w31);   // p1: keys 16-31
    pls(y00, y10); pls(y01, y11);   // p2: keys 32-47
    pls(y20, y30); pls(y21, y31);   // p3: keys 48-63
    short8 p0 = mk8(w00, w01, w10, w11);
    short8 p1 = mk8(w20, w21, w30, w31);
    short8 p2 = mk8(y00, y01, y10, y11);
    short8 p3 = mk8(y20, y21, y30, y31);

    // row-sum l via ones-MFMA: lacc[j] = sum_k P[q][k] for q=crow(j), every lane
    lacc = __builtin_amdgcn_mfma_f32_32x32x16_bf16(p0, onesf, lacc, 0, 0, 0);
    lacc = __builtin_amdgcn_mfma_f32_32x32x16_bf16(p1, onesf, lacc, 0, 0, 0);
    lacc = __builtin_amdgcn_mfma_f32_32x32x16_bf16(p2, onesf, lacc, 0, 0, 0);
    lacc = __builtin_amdgcn_mfma_f32_32x32x16_bf16(p3, onesf, lacc, 0, 0, 0);

    // PV: D[q][d] += P[q][k16] * V[k16][d]  (B-frag = V^T rows, swizzled reads)
#pragma unroll
    for (int kc = 0; kc < 4; ++kc) {
      short8 pa = kc == 0 ? p0 : kc == 1 ? p1 : kc == 2 ? p2 : p3;
      short8 v0 = *(const short8*)(Vb + krow0 + (((2 * kc + h2) ^ sw) * 8));
      o0 = __builtin_amdgcn_mfma_f32_32x32x16_bf16(pa, v0, o0, 0, 0, 0);
      short8 v1 = *(const short8*)(Vb + krow1 + (((2 * kc + h2) ^ sw) * 8));
      o1 = __builtin_amdgcn_mfma_f32_32x32x16_bf16(pa, v1, o1, 0, 0, 0);
    }
  }

  // epilogue: O row q = (j&3)+8*(j>>2)+4*h2, col d = 32*dt + c5; normalize by l[q]
  // lacc[j] holds l for row crow(j) on EVERY lane (ones-B makes all columns equal).
  u16* cbase = ctx + ((size_t)b * SS) * HID + hh * HD;
#pragma unroll
  for (int j = 0; j < 16; ++j) {
    const int row = (j & 3) + 8 * (j >> 2) + 4 * h2;
    const float ib = rcpr(lacc[j]);
    u16* crow = cbase + (size_t)(qbase + row) * HID;
    crow[c5]      = f2bf(o0[j] * ib);
    crow[32 + c5] = f2bf(o1[j] * ib);
  }
}

// ---------------------------------------------------------------------------------
extern "C" void kernel_launch(void* const* d_in, const int* in_sizes, int n_in,
                              void* d_out, int out_size, void* d_ws, size_t ws_size,
                              hipStream_t stream) {
  (void)in_sizes; (void)n_in; (void)out_size; (void)ws_size;
  const float* key   = (const float*)d_in[0];
  const float* value = (const float*)d_in[1];
  const float* query = (const float*)d_in[2];
  const float* mask  = (const float*)d_in[3];
  const float* Wq = (const float*)d_in[4];
  const float* bq = (const float*)d_in[5];
  const float* Wk = (const float*)d_in[6];
  const float* bk = (const float*)d_in[7];
  const float* Wv = (const float*)d_in[8];
  const float* bv = (const float*)d_in[9];
  const float* Wo = (const float*)d_in[10];
  const float* bo = (const float*)d_in[11];

  char* ws = (char*)d_ws;
  const size_t WSZ = (size_t)HID * HID * 2;         // one bf16 weight: 1.18 MB
  const size_t QSZ = (size_t)BB * NH * SS * HD * 2; // q/k/v/ctx bf16: 12.58 MB
  u16* w_t   = (u16*)ws;                            // 4 weights transposed (q,k,v,o)
  u16* q_bf  = (u16*)(ws + 4*WSZ);
  u16* k_bf  = (u16*)(ws + 4*WSZ + QSZ);
  u16* v_bf  = (u16*)(ws + 4*WSZ + 2*QSZ);
  u16* vt_bf = (u16*)(ws + 4*WSZ + 3*QSZ);
  u16* ctx   = (u16*)(ws + 4*WSZ + 4*QSZ);
  int* flag  = (int*)(ws + 4*WSZ + 5*QSZ);          // total ~64.5 MB

  hipMemsetAsync(flag, 0, 4, stream);
  mask_scan<<<2048, 256, 0, stream>>>((const uint4*)mask, (long long)BB*SS*SS/4, flag);
  w_transpose<<<dim3(12, 12, 4), 256, 0, stream>>>(Wq, Wk, Wv, Wo, w_t);
  proj_qkv<<<dim3(MM/128, HID/128, 3), 256, 0, stream>>>(query, key, value, w_t,
                                                         bq, bk, bv, q_bf, k_bf, v_bf);
  v_transpose<<<dim3(SS/64, BB*NH), 256, 0, stream>>>(v_bf, vt_bf);
  attn<<<dim3(SS/128, BB*NH), 256, 0, stream>>>(q_bf, k_bf, vt_bf, mask, flag, ctx);
  proj_out<<<dim3(MM/128, HID/128), 256, 0, stream>>>(ctx, w_t + 3*(size_t)HID*HID, bo,
                                                      (float*)d_out);
}